// Round 9
// baseline (171.222 us; speedup 1.0000x reference)
//
#include <hip/hip_runtime.h>

#define BATCH  512
#define K_OPS  16
#define D2     128
#define TSTEPS 64
#define NSLAB  (BATCH * TSTEPS)   // 32768 slabs of 16*128 floats (8 KB)

#define TAYB   256                // taylor blocks in K1
#define ZK1    1152               // K1 zero blocks: 16 slabs each -> slabs 0..18431 (batches 0..287)
#define CHAINB 256                // K2 chain blocks (2 batches per block, 1 wave each)
#define ZK2    1792               // K2 zero blocks: batches 288..511, 8 blocks/batch

typedef float vf4 __attribute__((ext_vector_type(4)));

__device__ inline int argmax16(const float* __restrict__ ub) {
    float m = ub[0]; int lab = 0;
    #pragma unroll
    for (int j = 1; j < K_OPS; ++j) {
        const float v = ub[j];
        if (v > m) { m = v; lab = j; }
    }
    return lab;
}

// ---------------------------------------------------------------------------
// K1: blocks 0..255 = labels + 10 Taylor orders with X ENTIRELY IN REGISTERS
//     (built from H on the fly; LDS only 21.5 KB -> zero blocks co-reside).
//     blocks 256..  = full-slab zero of batches 0..287 (144 MB, contiguous
//     NT streams; chains overwrite the label channel later in K2).
// ---------------------------------------------------------------------------
__global__ __launch_bounds__(256) void k_taylor(
    const float* __restrict__ H, const float* __restrict__ u,
    float* __restrict__ ACC, int* __restrict__ labels,
    float* __restrict__ out)
{
    const int bid = blockIdx.x, tid = threadIdx.x;

    if (bid >= TAYB) {
        // ---- full-slab zero: 16 consecutive slabs (128 KB contiguous) ----
        const int zb = bid - TAYB;
        const vf4 zv = {0.f, 0.f, 0.f, 0.f};
        float* base = out + (size_t)zb * 16 * 2048;
        #pragma unroll 4
        for (int s = 0; s < 16; ++s) {
            vf4* p = (vf4*)(base + (size_t)s * 2048);
            __builtin_nontemporal_store(zv, p + tid);
            __builtin_nontemporal_store(zv, p + tid + 256);
        }
        return;
    }

    __shared__ float PsT[D2][12];     // PsT[c][r] = P[r0+r][c]   (6 KB)
    __shared__ float Red[3][64][20];  // jg-partial reduction    (15.4 KB)

    // labels for K2 (16 blocks x 32 threads)
    if (bid < 16 && tid < 32) {
        const int b = bid * 32 + tid;
        labels[b] = argmax16(u + b * K_OPS);
    }

    const int k   = bid >> 4;
    const int r0s = (bid & 15) * 8;
    const float* Hk = H + (size_t)k * D2 * D2;

    const int jg = tid >> 6;            // wave index 0..3 (j-split)
    const int rg = (tid >> 5) & 1;
    const int cg = tid & 31;

    // ---- X for this thread's (jg, cg) slice, in registers ----
    // x[m][cc] = X[(m<<2)|jg][cg*4+cc],  X[i][j] = sgn(i)*0.5*(H[i^64][j]+H[j][i^64])
    float x[32][4];
    #pragma unroll
    for (int m = 0; m < 32; ++m) {
        const int j  = (m << 2) | jg;
        const int j2 = j ^ 64;
        const float sg = (j < 64) ? 0.5f : -0.5f;
        const float4 a = *(const float4*)&Hk[j2 * D2 + cg * 4];
        const float av[4] = {a.x, a.y, a.z, a.w};
        #pragma unroll
        for (int cc = 0; cc < 4; ++cc)
            x[m][cc] = sg * (av[cc] + Hk[(cg * 4 + cc) * D2 + j2]);
    }

    // ---- init PsT = X-strip transposed (all 256 threads: c = tid&127) ----
    {
        const int c = tid & 127, rh = tid >> 7;
        float4 v;
        float* vp = (float*)&v;
        #pragma unroll
        for (int rr = 0; rr < 4; ++rr) {
            const int row = r0s + rh * 4 + rr;
            const int row2 = row ^ 64;
            const float sg = (row < 64) ? 0.5f : -0.5f;
            vp[rr] = sg * (Hk[row2 * D2 + c] + Hk[c * D2 + row2]);
        }
        *(float4*)&PsT[c][rh * 4] = v;
    }

    // ---- acc = I + X (strip tile), wave 0 only ----
    float acc[4][4];
    if (jg == 0) {
        #pragma unroll
        for (int rr = 0; rr < 4; ++rr) {
            const int row = r0s + rg * 4 + rr;
            const int row2 = row ^ 64;
            const float sg = (row < 64) ? 0.5f : -0.5f;
            const float4 a = *(const float4*)&Hk[row2 * D2 + cg * 4];
            const float av[4] = {a.x, a.y, a.z, a.w};
            #pragma unroll
            for (int cc = 0; cc < 4; ++cc) {
                const float xv = sg * (av[cc] + Hk[(cg * 4 + cc) * D2 + row2]);
                acc[rr][cc] = xv + ((row == cg * 4 + cc) ? 1.0f : 0.0f);
            }
        }
    }
    __syncthreads();

    // ---- 9 remaining Taylor orders; X from registers, P broadcast via LDS ----
    for (int it = 2; it <= 10; ++it) {
        float nv[4][4] = {{0.f,0.f,0.f,0.f},{0.f,0.f,0.f,0.f},
                          {0.f,0.f,0.f,0.f},{0.f,0.f,0.f,0.f}};
        #pragma unroll 8
        for (int m = 0; m < 32; ++m) {
            const int j = (m << 2) | jg;
            const float4 pv = *(const float4*)&PsT[j][rg * 4];
            const float p[4] = {pv.x, pv.y, pv.z, pv.w};
            #pragma unroll
            for (int rr = 0; rr < 4; ++rr)
                #pragma unroll
                for (int cc = 0; cc < 4; ++cc)
                    nv[rr][cc] = fmaf(p[rr], x[m][cc], nv[rr][cc]);
        }
        if (jg != 0) {
            float* rb = Red[jg - 1][rg * 32 + cg];
            #pragma unroll
            for (int rr = 0; rr < 4; ++rr)
                *(float4*)&rb[rr * 4] =
                    make_float4(nv[rr][0], nv[rr][1], nv[rr][2], nv[rr][3]);
        }
        __syncthreads();
        if (jg == 0) {
            #pragma unroll
            for (int g = 0; g < 3; ++g) {
                const float* rb = Red[g][rg * 32 + cg];
                #pragma unroll
                for (int rr = 0; rr < 4; ++rr) {
                    const float4 p = *(const float4*)&rb[rr * 4];
                    nv[rr][0] += p.x; nv[rr][1] += p.y;
                    nv[rr][2] += p.z; nv[rr][3] += p.w;
                }
            }
            const float inv = 1.0f / (float)it;
            #pragma unroll
            for (int rr = 0; rr < 4; ++rr)
                #pragma unroll
                for (int cc = 0; cc < 4; ++cc) {
                    nv[rr][cc] *= inv;
                    acc[rr][cc] += nv[rr][cc];
                }
            #pragma unroll
            for (int cc = 0; cc < 4; ++cc)
                *(float4*)&PsT[cg * 4 + cc][rg * 4] =
                    make_float4(nv[0][cc], nv[1][cc], nv[2][cc], nv[3][cc]);
        }
        __syncthreads();
    }

    if (jg == 0) {
        float* Ak = ACC + ((size_t)k * D2 + r0s + rg * 4) * D2;
        #pragma unroll
        for (int rr = 0; rr < 4; ++rr)
            *(float4*)&Ak[rr * D2 + cg * 4] =
                make_float4(acc[rr][0], acc[rr][1], acc[rr][2], acc[rr][3]);
    }
}

// ---------------------------------------------------------------------------
// K2: blocks 0..255  = chains. 1 wave = 1 batch; lane l holds rows l and
//     l+64 of expH[lab] (256 VGPR); state broadcast via a per-wave 512 B LDS
//     buffer; NO barriers (wave-synchronous); outputs NT-stored directly.
//     blocks 256..   = label-skip zero of batches 288..511.
// ---------------------------------------------------------------------------
__global__ __launch_bounds__(128) void k_prop(
    const float* __restrict__ s_in, const float* __restrict__ ACC,
    const int* __restrict__ labels, float* __restrict__ out)
{
    const int bid = blockIdx.x, tid = threadIdx.x;

    if (bid >= CHAINB) {
        const int z = bid - CHAINB;            // 0..1791
        const int b = 288 + (z >> 3);
        const int sub = z & 7;                 // 8 slabs each
        const int lab = labels[b];
        const vf4 zv = {0.f, 0.f, 0.f, 0.f};
        float* base = out + (size_t)(b * TSTEPS + sub * 8) * 2048;
        #pragma unroll 4
        for (int s = 0; s < 8; ++s) {
            vf4* p = (vf4*)(base + (size_t)s * 2048);
            #pragma unroll
            for (int qq = 0; qq < 4; ++qq) {
                const int slot = tid + qq * 128;
                if ((slot >> 5) != lab) __builtin_nontemporal_store(zv, p + slot);
            }
        }
        return;
    }

    // ---- chain: wave w handles batch bid*2+w; lane l owns rows l, l+64 ----
    __shared__ float sbuf[2][D2];

    const int w = tid >> 6, l = tid & 63;
    const int b = bid * 2 + w;
    const int lab = labels[b];
    float* sb = sbuf[w];

    float rA[D2], rB[D2];
    {
        const float4* m0 = (const float4*)(ACC + ((size_t)lab * D2 + l) * D2);
        const float4* m1 = (const float4*)(ACC + ((size_t)lab * D2 + l + 64) * D2);
        #pragma unroll
        for (int jj = 0; jj < 32; ++jj) {
            const float4 a = m0[jj];
            rA[4*jj+0] = a.x; rA[4*jj+1] = a.y; rA[4*jj+2] = a.z; rA[4*jj+3] = a.w;
            const float4 c = m1[jj];
            rB[4*jj+0] = c.x; rB[4*jj+1] = c.y; rB[4*jj+2] = c.z; rB[4*jj+3] = c.w;
        }
    }

    float s0 = s_in[((size_t)b * K_OPS + lab) * D2 + l];
    float s1 = s_in[((size_t)b * K_OPS + lab) * D2 + l + 64];
    sb[l] = s0;
    sb[l + 64] = s1;

    float* ob = out + ((size_t)b * TSTEPS * K_OPS + lab) * D2;
    __builtin_nontemporal_store(s0, ob + l);
    __builtin_nontemporal_store(s1, ob + l + 64);

    for (int t = 1; t < TSTEPS; ++t) {
        float a0 = 0.f, a1 = 0.f;
        #pragma unroll
        for (int jj = 0; jj < 32; ++jj) {
            const float4 sv = *(const float4*)&sb[jj * 4];   // uniform: broadcast
            a0 = fmaf(rA[4*jj+0], sv.x, a0);
            a0 = fmaf(rA[4*jj+1], sv.y, a0);
            a0 = fmaf(rA[4*jj+2], sv.z, a0);
            a0 = fmaf(rA[4*jj+3], sv.w, a0);
            a1 = fmaf(rB[4*jj+0], sv.x, a1);
            a1 = fmaf(rB[4*jj+1], sv.y, a1);
            a1 = fmaf(rB[4*jj+2], sv.z, a1);
            a1 = fmaf(rB[4*jj+3], sv.w, a1);
        }
        // wave-synchronous exchange: same wave, aliasing keeps order; no barrier
        sb[l] = a0;
        sb[l + 64] = a1;
        float* op = ob + (size_t)t * K_OPS * D2;
        __builtin_nontemporal_store(a0, op + l);
        __builtin_nontemporal_store(a1, op + l + 64);
    }
}

extern "C" void kernel_launch(void* const* d_in, const int* in_sizes, int n_in,
                              void* d_out, int out_size, void* d_ws, size_t ws_size,
                              hipStream_t stream) {
    const float* u_t = (const float*)d_in[0];   // [512,16]
    const float* s_t = (const float*)d_in[1];   // [512,16,128]
    const float* H   = (const float*)d_in[2];   // [16,128,128]

    float* out    = (float*)d_out;
    float* Aw     = (float*)d_ws;                       // [16,128,128] = 1 MB
    int*   labels = (int*)(Aw + K_OPS * D2 * D2);       // [512]

    hipLaunchKernelGGL(k_taylor, dim3(TAYB + ZK1), dim3(256), 0, stream,
                       H, u_t, Aw, labels, out);
    hipLaunchKernelGGL(k_prop, dim3(CHAINB + ZK2), dim3(128), 0, stream,
                       s_t, Aw, labels, out);
}

// Round 10
// 137.448 us; speedup vs baseline: 1.2457x; 1.2457x over previous
//
#include <hip/hip_runtime.h>

#define BATCH  512
#define K_OPS  16
#define D2     128
#define TSTEPS 64

#define TAYB   256                // taylor blocks in K1
#define ZK1    960                // K1 zero blocks: 16 full slabs each -> batches 0..239
#define CHAINB 512                // K2 chain blocks (1 batch each, 2 waves)
#define ZK2    2176               // K2 zero blocks: batches 240..511, 8 slabs each

typedef float vf4 __attribute__((ext_vector_type(4)));

__device__ inline int argmax16(const float* __restrict__ ub) {
    float m = ub[0]; int lab = 0;
    #pragma unroll
    for (int j = 1; j < K_OPS; ++j) {
        const float v = ub[j];
        if (v > m) { m = v; lab = j; }
    }
    return lab;
}

// broadcast lane `lane` of v to all lanes (constant lane -> v_readlane_b32)
__device__ inline float bcast(float v, int lane) {
    return __uint_as_float(__builtin_amdgcn_readlane(__float_as_uint(v), lane));
}

// ---------------------------------------------------------------------------
// K1: blocks 0..255 = labels + 10 Taylor orders. X slice in REGISTERS
//     (x[32][4] = 128 VGPR), built from LDS-staged H (one-time cost).
//     LDS = union{Hs, Red} + PsT = 73.7 KB -> 2 blocks/CU, VGPR capped 256
//     -> one zero block co-resides per CU and streams writes while taylor
//     runs on VALU/LDS pipes.
//     blocks 256.. = full-slab zero of batches 0..239 (120 MB).
// ---------------------------------------------------------------------------
__global__ __launch_bounds__(256, 2) void k_taylor(
    const float* __restrict__ H, const float* __restrict__ u,
    float* __restrict__ ACC, int* __restrict__ labels,
    float* __restrict__ out)
{
    const int bid = blockIdx.x, tid = threadIdx.x;

    if (bid >= TAYB) {
        const int zb = bid - TAYB;
        const vf4 zv = {0.f, 0.f, 0.f, 0.f};
        float* base = out + (size_t)zb * 16 * 2048;
        #pragma unroll 4
        for (int s = 0; s < 16; ++s) {
            vf4* p = (vf4*)(base + (size_t)s * 2048);
            __builtin_nontemporal_store(zv, p + tid);
            __builtin_nontemporal_store(zv, p + tid + 256);
        }
        return;
    }

    __shared__ union {
        float Hs[D2][132];        // staging (dead after init)
        float Red[3][64][20];     // jg-partial reduction buffer
    } U;
    __shared__ float PsT[D2][12]; // PsT[c][r] = P[r0+r][c]

    if (bid < 16 && tid < 32) {
        const int b = bid * 32 + tid;
        labels[b] = argmax16(u + b * K_OPS);
    }

    const int k   = bid >> 4;
    const int r0s = (bid & 15) * 8;
    const float* Hk = H + (size_t)k * D2 * D2;

    // ---- stage H into padded LDS ----
    #pragma unroll
    for (int mm = 0; mm < 16; ++mm) {
        const int idx4 = tid + mm * 256;
        const float4 v = *(const float4*)&Hk[idx4 * 4];
        *(float4*)&U.Hs[idx4 >> 5][(idx4 & 31) * 4] = v;
    }
    __syncthreads();

    const int jg = tid >> 6;            // wave 0..3 (j-split)
    const int rg = (tid >> 5) & 1;
    const int cg = tid & 31;

    // ---- X slice in registers: x[m][cc] = X[(m<<2)|jg][cg*4+cc] ----
    // X[j][c] = sgn(j)*0.5*(H[j^64][c] + H[c][j^64])
    float x[32][4];
    #pragma unroll
    for (int m = 0; m < 32; ++m) {
        const int j = (m << 2) | jg, j2 = j ^ 64;
        const float sg = (j < 64) ? 0.5f : -0.5f;
        const float4 a = *(const float4*)&U.Hs[j2][cg * 4];
        const float av[4] = {a.x, a.y, a.z, a.w};
        #pragma unroll
        for (int cc = 0; cc < 4; ++cc)
            x[m][cc] = sg * (av[cc] + U.Hs[cg * 4 + cc][j2]);
    }

    // ---- PsT init: P^1 = X strip, transposed ----
    {
        const int c = tid & 127, rh = tid >> 7;
        float4 v; float* vp = (float*)&v;
        #pragma unroll
        for (int rr = 0; rr < 4; ++rr) {
            const int row = r0s + rh * 4 + rr, row2 = row ^ 64;
            const float sgr = (row < 64) ? 0.5f : -0.5f;
            vp[rr] = sgr * (U.Hs[row2][c] + U.Hs[c][row2]);
        }
        *(float4*)&PsT[c][rh * 4] = v;
    }

    // ---- acc = I + X (jg==0 tile) ----
    float acc[4][4];
    if (jg == 0) {
        #pragma unroll
        for (int rr = 0; rr < 4; ++rr) {
            const int row = r0s + rg * 4 + rr, row2 = row ^ 64;
            const float sgr = (row < 64) ? 0.5f : -0.5f;
            const float4 a = *(const float4*)&U.Hs[row2][cg * 4];
            const float av[4] = {a.x, a.y, a.z, a.w};
            #pragma unroll
            for (int cc = 0; cc < 4; ++cc) {
                const float xv = sgr * (av[cc] + U.Hs[cg * 4 + cc][row2]);
                acc[rr][cc] = xv + ((row == cg * 4 + cc) ? 1.0f : 0.0f);
            }
        }
    }
    __syncthreads();   // Hs reads done; Red may reuse the space

    // ---- 9 remaining Taylor orders ----
    for (int it = 2; it <= 10; ++it) {
        float nv[4][4] = {{0.f,0.f,0.f,0.f},{0.f,0.f,0.f,0.f},
                          {0.f,0.f,0.f,0.f},{0.f,0.f,0.f,0.f}};
        #pragma unroll 8
        for (int m = 0; m < 32; ++m) {
            const int j = (m << 2) | jg;
            const float4 pv = *(const float4*)&PsT[j][rg * 4];
            const float p[4] = {pv.x, pv.y, pv.z, pv.w};
            #pragma unroll
            for (int rr = 0; rr < 4; ++rr)
                #pragma unroll
                for (int cc = 0; cc < 4; ++cc)
                    nv[rr][cc] = fmaf(p[rr], x[m][cc], nv[rr][cc]);
        }
        if (jg != 0) {
            float* rb = U.Red[jg - 1][rg * 32 + cg];
            #pragma unroll
            for (int rr = 0; rr < 4; ++rr)
                *(float4*)&rb[rr * 4] =
                    make_float4(nv[rr][0], nv[rr][1], nv[rr][2], nv[rr][3]);
        }
        __syncthreads();
        if (jg == 0) {
            #pragma unroll
            for (int g = 0; g < 3; ++g) {
                const float* rb = U.Red[g][rg * 32 + cg];
                #pragma unroll
                for (int rr = 0; rr < 4; ++rr) {
                    const float4 p = *(const float4*)&rb[rr * 4];
                    nv[rr][0] += p.x; nv[rr][1] += p.y;
                    nv[rr][2] += p.z; nv[rr][3] += p.w;
                }
            }
            const float inv = 1.0f / (float)it;
            #pragma unroll
            for (int rr = 0; rr < 4; ++rr)
                #pragma unroll
                for (int cc = 0; cc < 4; ++cc) {
                    nv[rr][cc] *= inv;
                    acc[rr][cc] += nv[rr][cc];
                }
            #pragma unroll
            for (int cc = 0; cc < 4; ++cc)
                *(float4*)&PsT[cg * 4 + cc][rg * 4] =
                    make_float4(nv[0][cc], nv[1][cc], nv[2][cc], nv[3][cc]);
        }
        __syncthreads();
    }

    if (jg == 0) {
        float* Ak = ACC + ((size_t)k * D2 + r0s + rg * 4) * D2;
        #pragma unroll
        for (int rr = 0; rr < 4; ++rr)
            *(float4*)&Ak[rr * D2 + cg * 4] =
                make_float4(acc[rr][0], acc[rr][1], acc[rr][2], acc[rr][3]);
    }
}

// ---------------------------------------------------------------------------
// K2: blocks 0..511 = chains. 1 batch/block, 2 waves; lane l owns row
//     w*64+l (row[128] VGPR). s broadcast via v_readlane (NO LDS pipe in the
//     FMA loop). Cross-wave exchange: 1 KB double-buffered LDS + inline-asm
//     barrier that waits lgkm only (NT store stream never drained).
//     blocks 512.. = label-skip zero of batches 240..511.
// ---------------------------------------------------------------------------
__global__ __launch_bounds__(128, 2) void k_prop(
    const float* __restrict__ s_in, const float* __restrict__ ACC,
    const int* __restrict__ labels, float* __restrict__ out)
{
    const int bid = blockIdx.x, tid = threadIdx.x;

    if (bid >= CHAINB) {
        const int z = bid - CHAINB;            // 0..2175
        const int b = 240 + (z >> 3);
        const int sub = z & 7;
        const int lab = labels[b];
        const vf4 zv = {0.f, 0.f, 0.f, 0.f};
        float* base = out + ((size_t)b * TSTEPS + sub * 8) * (K_OPS * D2);
        #pragma unroll 4
        for (int s = 0; s < 8; ++s) {
            vf4* p = (vf4*)(base + (size_t)s * K_OPS * D2);
            #pragma unroll
            for (int q = 0; q < 4; ++q) {
                const int slot = tid + q * 128;
                if ((slot >> 5) != lab) __builtin_nontemporal_store(zv, p + slot);
            }
        }
        return;
    }

    __shared__ float xch[2][D2];

    const int w = tid >> 6, l = tid & 63;
    const int b = bid;
    const int lab = labels[b];

    // lane l of wave w owns row w*64+l (128 VGPR, per-lane contiguous -> L1)
    float row[D2];
    {
        const float4* rp = (const float4*)(ACC + ((size_t)lab * D2 + w * 64 + l) * D2);
        #pragma unroll
        for (int jj = 0; jj < 32; ++jj) {
            const float4 v = rp[jj];
            row[4*jj+0] = v.x; row[4*jj+1] = v.y;
            row[4*jj+2] = v.z; row[4*jj+3] = v.w;
        }
    }

    const float* sb = s_in + ((size_t)b * K_OPS + lab) * D2;
    float sLo = sb[l];        // each wave holds the FULL state: s[l], s[l+64]
    float sHi = sb[l + 64];

    float* ob = out + ((size_t)b * TSTEPS * K_OPS + lab) * D2 + w * 64 + l;
    __builtin_nontemporal_store((w == 0) ? sLo : sHi, ob);   // t = 0

    for (int t = 1; t < TSTEPS; ++t) {
        float y = 0.f;
        #pragma unroll
        for (int j = 0; j < 64; ++j)
            y = fmaf(row[j], bcast(sLo, j), y);
        #pragma unroll
        for (int j = 0; j < 64; ++j)
            y = fmaf(row[64 + j], bcast(sHi, j), y);

        __builtin_nontemporal_store(y, ob + (size_t)t * (K_OPS * D2));

        // cross-wave exchange (double-buffered; lgkm-only barrier)
        xch[t & 1][w * 64 + l] = y;
        asm volatile("s_waitcnt lgkmcnt(0)\n\ts_barrier" ::: "memory");
        const float other = xch[t & 1][(w ^ 1) * 64 + l];
        const bool w0 = (w == 0);
        sLo = w0 ? y : other;
        sHi = w0 ? other : y;
    }
}

extern "C" void kernel_launch(void* const* d_in, const int* in_sizes, int n_in,
                              void* d_out, int out_size, void* d_ws, size_t ws_size,
                              hipStream_t stream) {
    const float* u_t = (const float*)d_in[0];   // [512,16]
    const float* s_t = (const float*)d_in[1];   // [512,16,128]
    const float* H   = (const float*)d_in[2];   // [16,128,128]

    float* out    = (float*)d_out;
    float* Aw     = (float*)d_ws;                       // [16,128,128] = 1 MB
    int*   labels = (int*)(Aw + K_OPS * D2 * D2);       // [512]

    hipLaunchKernelGGL(k_taylor, dim3(TAYB + ZK1), dim3(256), 0, stream,
                       H, u_t, Aw, labels, out);
    hipLaunchKernelGGL(k_prop, dim3(CHAINB + ZK2), dim3(128), 0, stream,
                       s_t, Aw, labels, out);
}

// Round 11
// 113.609 us; speedup vs baseline: 1.5071x; 1.2098x over previous
//
#include <hip/hip_runtime.h>

#define BATCH  512
#define K_OPS  16
#define D2     128
#define TSTEPS 64

#define TAYB   256                // taylor blocks in K1
#define ZK1    960                // K1 zero blocks: 16 full slabs each -> batches 0..239
#define CHAINB 512                // K2 chain blocks (1 batch each, 2 waves)
#define ZK2    2176               // K2 zero blocks: batches 240..511, 8 slabs each

typedef float vf4 __attribute__((ext_vector_type(4)));

__device__ inline int argmax16(const float* __restrict__ ub) {
    float m = ub[0]; int lab = 0;
    #pragma unroll
    for (int j = 1; j < K_OPS; ++j) {
        const float v = ub[j];
        if (v > m) { m = v; lab = j; }
    }
    return lab;
}

// broadcast lane `lane` of v to all lanes (constant lane -> v_readlane_b32)
__device__ inline float bcast(float v, int lane) {
    return __uint_as_float(__builtin_amdgcn_readlane(__float_as_uint(v), lane));
}

// ---------------------------------------------------------------------------
// K1: blocks 0..255 = labels + 10 Taylor orders. X slice in REGISTERS
//     (x[32][4] = 128 VGPR, ALL indices compile-time static -> no scratch).
//     LDS = union{Hs, Red} + PsT = 73.6 KB -> 2 blocks/CU, so zero blocks
//     co-reside and stream writes while taylor runs on the VALU.
//     blocks 256.. = full-slab zero of batches 0..239 (120 MB).
// ---------------------------------------------------------------------------
__global__ __launch_bounds__(256, 2) void k_taylor(
    const float* __restrict__ H, const float* __restrict__ u,
    float* __restrict__ ACC, int* __restrict__ labels,
    float* __restrict__ out)
{
    const int bid = blockIdx.x, tid = threadIdx.x;

    if (bid >= TAYB) {
        const int zb = bid - TAYB;
        const vf4 zv = {0.f, 0.f, 0.f, 0.f};
        float* base = out + (size_t)zb * 16 * 2048;
        #pragma unroll 4
        for (int s = 0; s < 16; ++s) {
            vf4* p = (vf4*)(base + (size_t)s * 2048);
            __builtin_nontemporal_store(zv, p + tid);
            __builtin_nontemporal_store(zv, p + tid + 256);
        }
        return;
    }

    __shared__ union {
        float Hs[D2][132];        // staging (dead after init)
        float Red[3][64][20];     // jg-partial reduction buffer
    } U;
    __shared__ float PsT[D2][12]; // PsT[c][r] = P[r0+r][c]

    if (bid < 16 && tid < 32) {
        const int b = bid * 32 + tid;
        labels[b] = argmax16(u + b * K_OPS);
    }

    const int k   = bid >> 4;
    const int r0s = (bid & 15) * 8;
    const float* Hk = H + (size_t)k * D2 * D2;

    // ---- stage H into padded LDS ----
    #pragma unroll
    for (int mm = 0; mm < 16; ++mm) {
        const int idx4 = tid + mm * 256;
        const float4 v = *(const float4*)&Hk[idx4 * 4];
        *(float4*)&U.Hs[idx4 >> 5][(idx4 & 31) * 4] = v;
    }
    __syncthreads();

    const int jg = tid >> 6;            // wave 0..3 (j-split)
    const int rg = (tid >> 5) & 1;
    const int cg = tid & 31;

    // ---- X slice in registers: x[m][cc] = X[(m<<2)|jg][cg*4+cc] ----
    // X[j][c] = sgn(j)*0.5*(H[j^64][c] + H[c][j^64])
    float x[32][4];
    #pragma unroll
    for (int m = 0; m < 32; ++m) {
        const int j = (m << 2) | jg, j2 = j ^ 64;
        const float sg = (j < 64) ? 0.5f : -0.5f;
        const float4 a = *(const float4*)&U.Hs[j2][cg * 4];
        const float av[4] = {a.x, a.y, a.z, a.w};
        #pragma unroll
        for (int cc = 0; cc < 4; ++cc)
            x[m][cc] = sg * (av[cc] + U.Hs[cg * 4 + cc][j2]);
    }

    // ---- PsT init: P^1 = X strip, transposed ----
    {
        const int c = tid & 127, rh = tid >> 7;
        float4 v; float* vp = (float*)&v;
        #pragma unroll
        for (int rr = 0; rr < 4; ++rr) {
            const int row = r0s + rh * 4 + rr, row2 = row ^ 64;
            const float sgr = (row < 64) ? 0.5f : -0.5f;
            vp[rr] = sgr * (U.Hs[row2][c] + U.Hs[c][row2]);
        }
        *(float4*)&PsT[c][rh * 4] = v;
    }

    // ---- acc = I + X (jg==0 tile) ----
    float acc[4][4];
    if (jg == 0) {
        #pragma unroll
        for (int rr = 0; rr < 4; ++rr) {
            const int row = r0s + rg * 4 + rr, row2 = row ^ 64;
            const float sgr = (row < 64) ? 0.5f : -0.5f;
            const float4 a = *(const float4*)&U.Hs[row2][cg * 4];
            const float av[4] = {a.x, a.y, a.z, a.w};
            #pragma unroll
            for (int cc = 0; cc < 4; ++cc) {
                const float xv = sgr * (av[cc] + U.Hs[cg * 4 + cc][row2]);
                acc[rr][cc] = xv + ((row == cg * 4 + cc) ? 1.0f : 0.0f);
            }
        }
    }
    __syncthreads();   // Hs reads done; Red may reuse the space

    // ---- 9 remaining Taylor orders (m-loop FULLY unrolled: x stays VGPR) ----
    for (int it = 2; it <= 10; ++it) {
        float nv[4][4] = {{0.f,0.f,0.f,0.f},{0.f,0.f,0.f,0.f},
                          {0.f,0.f,0.f,0.f},{0.f,0.f,0.f,0.f}};
        #pragma unroll
        for (int m = 0; m < 32; ++m) {
            const int j = (m << 2) | jg;
            const float4 pv = *(const float4*)&PsT[j][rg * 4];
            const float p[4] = {pv.x, pv.y, pv.z, pv.w};
            #pragma unroll
            for (int rr = 0; rr < 4; ++rr)
                #pragma unroll
                for (int cc = 0; cc < 4; ++cc)
                    nv[rr][cc] = fmaf(p[rr], x[m][cc], nv[rr][cc]);
        }
        if (jg != 0) {
            float* rb = U.Red[jg - 1][rg * 32 + cg];
            #pragma unroll
            for (int rr = 0; rr < 4; ++rr)
                *(float4*)&rb[rr * 4] =
                    make_float4(nv[rr][0], nv[rr][1], nv[rr][2], nv[rr][3]);
        }
        __syncthreads();
        if (jg == 0) {
            #pragma unroll
            for (int g = 0; g < 3; ++g) {
                const float* rb = U.Red[g][rg * 32 + cg];
                #pragma unroll
                for (int rr = 0; rr < 4; ++rr) {
                    const float4 p = *(const float4*)&rb[rr * 4];
                    nv[rr][0] += p.x; nv[rr][1] += p.y;
                    nv[rr][2] += p.z; nv[rr][3] += p.w;
                }
            }
            const float inv = 1.0f / (float)it;
            #pragma unroll
            for (int rr = 0; rr < 4; ++rr)
                #pragma unroll
                for (int cc = 0; cc < 4; ++cc) {
                    nv[rr][cc] *= inv;
                    acc[rr][cc] += nv[rr][cc];
                }
            #pragma unroll
            for (int cc = 0; cc < 4; ++cc)
                *(float4*)&PsT[cg * 4 + cc][rg * 4] =
                    make_float4(nv[0][cc], nv[1][cc], nv[2][cc], nv[3][cc]);
        }
        __syncthreads();
    }

    if (jg == 0) {
        float* Ak = ACC + ((size_t)k * D2 + r0s + rg * 4) * D2;
        #pragma unroll
        for (int rr = 0; rr < 4; ++rr)
            *(float4*)&Ak[rr * D2 + cg * 4] =
                make_float4(acc[rr][0], acc[rr][1], acc[rr][2], acc[rr][3]);
    }
}

// ---------------------------------------------------------------------------
// K2: blocks 0..511 = chains. 1 batch/block, 2 waves; lane l owns row
//     w*64+l (row[128] VGPR, static indices). s broadcast via v_readlane
//     (no LDS pipe in the FMA loop). Cross-wave exchange: 1 KB double-
//     buffered LDS + lgkm-only inline-asm barrier (NT stores free-run).
//     blocks 512.. = label-skip zero of batches 240..511.
// ---------------------------------------------------------------------------
__global__ __launch_bounds__(128, 2) void k_prop(
    const float* __restrict__ s_in, const float* __restrict__ ACC,
    const int* __restrict__ labels, float* __restrict__ out)
{
    const int bid = blockIdx.x, tid = threadIdx.x;

    if (bid >= CHAINB) {
        const int z = bid - CHAINB;            // 0..2175
        const int b = 240 + (z >> 3);
        const int sub = z & 7;
        const int lab = labels[b];
        const vf4 zv = {0.f, 0.f, 0.f, 0.f};
        float* base = out + ((size_t)b * TSTEPS + sub * 8) * (K_OPS * D2);
        #pragma unroll 4
        for (int s = 0; s < 8; ++s) {
            vf4* p = (vf4*)(base + (size_t)s * K_OPS * D2);
            #pragma unroll
            for (int q = 0; q < 4; ++q) {
                const int slot = tid + q * 128;
                if ((slot >> 5) != lab) __builtin_nontemporal_store(zv, p + slot);
            }
        }
        return;
    }

    __shared__ float xch[2][D2];

    const int w = tid >> 6, l = tid & 63;
    const int b = bid;
    const int lab = labels[b];

    // lane l of wave w owns row w*64+l (128 VGPR, static unroll)
    float row[D2];
    {
        const float4* rp = (const float4*)(ACC + ((size_t)lab * D2 + w * 64 + l) * D2);
        #pragma unroll
        for (int jj = 0; jj < 32; ++jj) {
            const float4 v = rp[jj];
            row[4*jj+0] = v.x; row[4*jj+1] = v.y;
            row[4*jj+2] = v.z; row[4*jj+3] = v.w;
        }
    }

    const float* sb = s_in + ((size_t)b * K_OPS + lab) * D2;
    float sLo = sb[l];        // each wave holds the FULL state: s[l], s[l+64]
    float sHi = sb[l + 64];

    float* ob = out + ((size_t)b * TSTEPS * K_OPS + lab) * D2 + w * 64 + l;
    __builtin_nontemporal_store((w == 0) ? sLo : sHi, ob);   // t = 0

    for (int t = 1; t < TSTEPS; ++t) {
        float y = 0.f;
        #pragma unroll
        for (int j = 0; j < 64; ++j)
            y = fmaf(row[j], bcast(sLo, j), y);
        #pragma unroll
        for (int j = 0; j < 64; ++j)
            y = fmaf(row[64 + j], bcast(sHi, j), y);

        __builtin_nontemporal_store(y, ob + (size_t)t * (K_OPS * D2));

        // cross-wave exchange (double-buffered; lgkm-only barrier)
        xch[t & 1][w * 64 + l] = y;
        asm volatile("s_waitcnt lgkmcnt(0)\n\ts_barrier" ::: "memory");
        const float other = xch[t & 1][(w ^ 1) * 64 + l];
        const bool w0 = (w == 0);
        sLo = w0 ? y : other;
        sHi = w0 ? other : y;
    }
}

extern "C" void kernel_launch(void* const* d_in, const int* in_sizes, int n_in,
                              void* d_out, int out_size, void* d_ws, size_t ws_size,
                              hipStream_t stream) {
    const float* u_t = (const float*)d_in[0];   // [512,16]
    const float* s_t = (const float*)d_in[1];   // [512,16,128]
    const float* H   = (const float*)d_in[2];   // [16,128,128]

    float* out    = (float*)d_out;
    float* Aw     = (float*)d_ws;                       // [16,128,128] = 1 MB
    int*   labels = (int*)(Aw + K_OPS * D2 * D2);       // [512]

    hipLaunchKernelGGL(k_taylor, dim3(TAYB + ZK1), dim3(256), 0, stream,
                       H, u_t, Aw, labels, out);
    hipLaunchKernelGGL(k_prop, dim3(CHAINB + ZK2), dim3(128), 0, stream,
                       s_t, Aw, labels, out);
}

// Round 12
// 87.235 us; speedup vs baseline: 1.9628x; 1.3023x over previous
//
#include <hip/hip_runtime.h>

#define BATCH  512
#define K_OPS  16
#define D2     128
#define TSTEPS 64
#define NSLAB  (BATCH * TSTEPS)   // 32768 slabs of 16*128 floats (8 KB)
#define CHAINB 512                // chain blocks in K2
#define ZEROB  2048               // zero blocks in K2 (strided over all slabs)

typedef float vf4 __attribute__((ext_vector_type(4)));

__device__ inline int argmax16(const float* __restrict__ ub) {
    float m = ub[0]; int lab = 0;
    #pragma unroll
    for (int j = 1; j < K_OPS; ++j) {
        const float v = ub[j];
        if (v > m) { m = v; lab = j; }
    }
    return lab;
}

// ---------------------------------------------------------------------------
// K1: labels + 10 Taylor orders, X slice in REGISTERS (x[32][4], all static
// indices). LDS = union{Hs,Red} + PsT = 72 KB. Grid = 256 (taylor only —
// no zero blocks: isolating taylor-regX standalone cost this round).
// ---------------------------------------------------------------------------
__global__ __launch_bounds__(256, 2) void k_taylor(
    const float* __restrict__ H, const float* __restrict__ u,
    float* __restrict__ ACC, int* __restrict__ labels)
{
    __shared__ union {
        float Hs[D2][132];        // staging (dead after init)
        float Red[3][64][20];     // jg-partial reduction buffer
    } U;
    __shared__ float PsT[D2][12]; // PsT[c][r] = P[r0+r][c]

    const int bid = blockIdx.x, tid = threadIdx.x;

    if (bid < 16 && tid < 32) {
        const int b = bid * 32 + tid;
        labels[b] = argmax16(u + b * K_OPS);
    }

    const int k   = bid >> 4;
    const int r0s = (bid & 15) * 8;
    const float* Hk = H + (size_t)k * D2 * D2;

    // ---- stage H into padded LDS ----
    #pragma unroll
    for (int mm = 0; mm < 16; ++mm) {
        const int idx4 = tid + mm * 256;
        const float4 v = *(const float4*)&Hk[idx4 * 4];
        *(float4*)&U.Hs[idx4 >> 5][(idx4 & 31) * 4] = v;
    }
    __syncthreads();

    const int jg = tid >> 6;            // wave 0..3 (j-split)
    const int rg = (tid >> 5) & 1;
    const int cg = tid & 31;

    // ---- X slice in registers: x[m][cc] = X[(m<<2)|jg][cg*4+cc] ----
    float x[32][4];
    #pragma unroll
    for (int m = 0; m < 32; ++m) {
        const int j = (m << 2) | jg, j2 = j ^ 64;
        const float sg = (j < 64) ? 0.5f : -0.5f;
        const float4 a = *(const float4*)&U.Hs[j2][cg * 4];
        const float av[4] = {a.x, a.y, a.z, a.w};
        #pragma unroll
        for (int cc = 0; cc < 4; ++cc)
            x[m][cc] = sg * (av[cc] + U.Hs[cg * 4 + cc][j2]);
    }

    // ---- PsT init: P^1 = X strip, transposed ----
    {
        const int c = tid & 127, rh = tid >> 7;
        float4 v; float* vp = (float*)&v;
        #pragma unroll
        for (int rr = 0; rr < 4; ++rr) {
            const int row = r0s + rh * 4 + rr, row2 = row ^ 64;
            const float sgr = (row < 64) ? 0.5f : -0.5f;
            vp[rr] = sgr * (U.Hs[row2][c] + U.Hs[c][row2]);
        }
        *(float4*)&PsT[c][rh * 4] = v;
    }

    // ---- acc = I + X (jg==0 tile) ----
    float acc[4][4];
    if (jg == 0) {
        #pragma unroll
        for (int rr = 0; rr < 4; ++rr) {
            const int row = r0s + rg * 4 + rr, row2 = row ^ 64;
            const float sgr = (row < 64) ? 0.5f : -0.5f;
            const float4 a = *(const float4*)&U.Hs[row2][cg * 4];
            const float av[4] = {a.x, a.y, a.z, a.w};
            #pragma unroll
            for (int cc = 0; cc < 4; ++cc) {
                const float xv = sgr * (av[cc] + U.Hs[cg * 4 + cc][row2]);
                acc[rr][cc] = xv + ((row == cg * 4 + cc) ? 1.0f : 0.0f);
            }
        }
    }
    __syncthreads();   // Hs reads done; Red reuses the space

    // ---- 9 remaining Taylor orders (m-loop fully unrolled; x stays VGPR) ----
    for (int it = 2; it <= 10; ++it) {
        float nv[4][4] = {{0.f,0.f,0.f,0.f},{0.f,0.f,0.f,0.f},
                          {0.f,0.f,0.f,0.f},{0.f,0.f,0.f,0.f}};
        #pragma unroll
        for (int m = 0; m < 32; ++m) {
            const int j = (m << 2) | jg;
            const float4 pv = *(const float4*)&PsT[j][rg * 4];
            const float p[4] = {pv.x, pv.y, pv.z, pv.w};
            #pragma unroll
            for (int rr = 0; rr < 4; ++rr)
                #pragma unroll
                for (int cc = 0; cc < 4; ++cc)
                    nv[rr][cc] = fmaf(p[rr], x[m][cc], nv[rr][cc]);
        }
        if (jg != 0) {
            float* rb = U.Red[jg - 1][rg * 32 + cg];
            #pragma unroll
            for (int rr = 0; rr < 4; ++rr)
                *(float4*)&rb[rr * 4] =
                    make_float4(nv[rr][0], nv[rr][1], nv[rr][2], nv[rr][3]);
        }
        __syncthreads();
        if (jg == 0) {
            #pragma unroll
            for (int g = 0; g < 3; ++g) {
                const float* rb = U.Red[g][rg * 32 + cg];
                #pragma unroll
                for (int rr = 0; rr < 4; ++rr) {
                    const float4 p = *(const float4*)&rb[rr * 4];
                    nv[rr][0] += p.x; nv[rr][1] += p.y;
                    nv[rr][2] += p.z; nv[rr][3] += p.w;
                }
            }
            const float inv = 1.0f / (float)it;
            #pragma unroll
            for (int rr = 0; rr < 4; ++rr)
                #pragma unroll
                for (int cc = 0; cc < 4; ++cc) {
                    nv[rr][cc] *= inv;
                    acc[rr][cc] += nv[rr][cc];
                }
            #pragma unroll
            for (int cc = 0; cc < 4; ++cc)
                *(float4*)&PsT[cg * 4 + cc][rg * 4] =
                    make_float4(nv[0][cc], nv[1][cc], nv[2][cc], nv[3][cc]);
        }
        __syncthreads();
    }

    if (jg == 0) {
        float* Ak = ACC + ((size_t)k * D2 + r0s + rg * 4) * D2;
        #pragma unroll
        for (int rr = 0; rr < 4; ++rr)
            *(float4*)&Ak[rr * D2 + cg * 4] =
                make_float4(acc[rr][0], acc[rr][1], acc[rr][2], acc[rr][3]);
    }
}

// ---------------------------------------------------------------------------
// K2: R6-verbatim. blocks 0..511 = per-batch chains (trajectory in LDS,
// barriers drain lgkm only — no vmem in the loop); blocks 512+ = label-skip
// zero blocks strided over all 32768 slabs.
// ---------------------------------------------------------------------------
__global__ __launch_bounds__(128) void k_prop(
    const float* __restrict__ s_in, const float* __restrict__ ACC,
    const int* __restrict__ labels, float* __restrict__ out)
{
    const int bid = blockIdx.x, tid = threadIdx.x;

    if (bid >= CHAINB) {
        const int z = bid - CHAINB;
        const vf4 zv = {0.f, 0.f, 0.f, 0.f};
        for (int slab = z; slab < NSLAB; slab += ZEROB) {
            const int lab = labels[slab >> 6];
            vf4* p = (vf4*)(out + (size_t)slab * 2048);
            #pragma unroll
            for (int q = 0; q < 4; ++q) {
                const int slot = tid + q * 128;
                if ((slot >> 5) != lab) __builtin_nontemporal_store(zv, p + slot);
            }
        }
        return;
    }

    // ---- chain path: one batch per block, thread i owns row i ----
    __shared__ float s_lds[D2];
    __shared__ float out_lds[TSTEPS][D2];   // 32 KB trajectory buffer

    const int b = bid, i = tid;
    const int lab = labels[b];

    float row[D2];
    const float4* rowp = (const float4*)(ACC + ((size_t)lab * D2 + i) * D2);
    #pragma unroll
    for (int jj = 0; jj < 32; ++jj) {
        const float4 rv = rowp[jj];
        row[4 * jj + 0] = rv.x; row[4 * jj + 1] = rv.y;
        row[4 * jj + 2] = rv.z; row[4 * jj + 3] = rv.w;
    }

    float sval = s_in[((size_t)b * K_OPS + lab) * D2 + i];
    s_lds[i] = sval;
    out_lds[0][i] = sval;
    __syncthreads();

    for (int t = 1; t < TSTEPS; ++t) {
        float acc = 0.f;
        const float4* s4 = (const float4*)s_lds;
        #pragma unroll
        for (int jj = 0; jj < 32; ++jj) {
            const float4 sv = s4[jj];
            acc = fmaf(row[4 * jj + 0], sv.x, acc);
            acc = fmaf(row[4 * jj + 1], sv.y, acc);
            acc = fmaf(row[4 * jj + 2], sv.z, acc);
            acc = fmaf(row[4 * jj + 3], sv.w, acc);
        }
        __syncthreads();              // reads of s_lds done (lgkm only)
        s_lds[i] = acc;
        out_lds[t][i] = acc;
        __syncthreads();              // new state visible (lgkm only)
    }

    // ---- bulk store: 32 KB coalesced, fire-and-forget ----
    const float* ol = &out_lds[0][0];
    float* ob = out + ((size_t)b * TSTEPS * K_OPS + lab) * D2;
    #pragma unroll
    for (int q = 0; q < 16; ++q) {
        const int s  = tid + q * 128;        // 0..2047 float4 slots
        const int t  = s >> 5;
        const int c4 = s & 31;
        const vf4 v = *(const vf4*)(ol + s * 4);
        __builtin_nontemporal_store(v, (vf4*)(ob + (size_t)t * K_OPS * D2) + c4);
    }
}

extern "C" void kernel_launch(void* const* d_in, const int* in_sizes, int n_in,
                              void* d_out, int out_size, void* d_ws, size_t ws_size,
                              hipStream_t stream) {
    const float* u_t = (const float*)d_in[0];   // [512,16]
    const float* s_t = (const float*)d_in[1];   // [512,16,128]
    const float* H   = (const float*)d_in[2];   // [16,128,128]

    float* out    = (float*)d_out;
    float* Aw     = (float*)d_ws;                       // [16,128,128] = 1 MB
    int*   labels = (int*)(Aw + K_OPS * D2 * D2);       // [512]

    hipLaunchKernelGGL(k_taylor, dim3(256), dim3(256), 0, stream,
                       H, u_t, Aw, labels);
    hipLaunchKernelGGL(k_prop, dim3(CHAINB + ZEROB), dim3(128), 0, stream,
                       s_t, Aw, labels, out);
}

// Round 13
// 77.040 us; speedup vs baseline: 2.2225x; 1.1323x over previous
//
#include <hip/hip_runtime.h>

#define BATCH  512
#define K_OPS  16
#define D2     128
#define TSTEPS 64

#define TAYB   256                // taylor blocks in K1
#define ZK1    1024               // K1 zero blocks: 16 full slabs -> batches 0..255
#define CHAINB 512                // K2 chain blocks (1 batch, 128 thr, 2 waves)
#define ZK2    2048               // K2 zero blocks: batches 256..511, 8 slabs each

typedef float vf4 __attribute__((ext_vector_type(4)));

__device__ inline int argmax16(const float* __restrict__ ub) {
    float m = ub[0]; int lab = 0;
    #pragma unroll
    for (int j = 1; j < K_OPS; ++j) {
        const float v = ub[j];
        if (v > m) { m = v; lab = j; }
    }
    return lab;
}

// ---------------------------------------------------------------------------
// K0: X_k = S@sym(H_k) -> global, + labels. 16 blocks. (R8-proven.)
// ---------------------------------------------------------------------------
__global__ __launch_bounds__(256) void k_xbuild(
    const float* __restrict__ H, const float* __restrict__ u,
    float* __restrict__ X, int* __restrict__ labels)
{
    __shared__ float Hs[D2][132];   // padded: column reads 4-way worst
    const int k = blockIdx.x, tid = threadIdx.x;

    if (tid < 32) labels[k * 32 + tid] = argmax16(u + (k * 32 + tid) * K_OPS);

    const float* Hk = H + (size_t)k * D2 * D2;
    #pragma unroll
    for (int mm = 0; mm < 16; ++mm) {
        const int idx4 = tid + mm * 256;
        const float4 v = *(const float4*)&Hk[idx4 * 4];
        *(float4*)&Hs[idx4 >> 5][(idx4 & 31) * 4] = v;
    }
    __syncthreads();

    float* Xk = X + (size_t)k * D2 * D2;
    #pragma unroll 4
    for (int m = 0; m < 64; ++m) {
        const int idx = tid + m * 256;
        const int i = idx >> 7, j = idx & 127;
        const int i2 = i ^ 64;
        const float sgn = (i < 64) ? 0.5f : -0.5f;
        Xk[idx] = sgn * (Hs[i2][j] + Hs[j][i2]);
    }
}

// ---------------------------------------------------------------------------
// K1: blocks 0..255 = 10 Taylor orders; X slice in registers loaded from
//     GLOBAL X via coalesced row reads (no LDS bank-conflict build).
//     LDS = PsT + Red = 21.5 KB -> 2 blocks/CU; zero blocks co-reside.
//     blocks 256.. = full-slab zero of batches 0..255 (128 MB).
// ---------------------------------------------------------------------------
__global__ __launch_bounds__(256, 2) void k_taylor(
    const float* __restrict__ X, float* __restrict__ ACC,
    float* __restrict__ out)
{
    const int bid = blockIdx.x, tid = threadIdx.x;

    if (bid >= TAYB) {
        const int zb = bid - TAYB;
        const vf4 zv = {0.f, 0.f, 0.f, 0.f};
        float* base = out + (size_t)zb * 16 * 2048;
        #pragma unroll 4
        for (int s = 0; s < 16; ++s) {
            vf4* p = (vf4*)(base + (size_t)s * 2048);
            __builtin_nontemporal_store(zv, p + tid);
            __builtin_nontemporal_store(zv, p + tid + 256);
        }
        return;
    }

    __shared__ float PsT[D2][12];     // PsT[c][r] = P[r0+r][c]   (6 KB)
    __shared__ float Red[3][64][20];  // jg-partial reduction    (15.4 KB)

    const int k   = bid >> 4;
    const int r0s = (bid & 15) * 8;
    const float* Xk = X + (size_t)k * D2 * D2;

    const int jg = tid >> 6;            // wave 0..3 (j-split)
    const int rg = (tid >> 5) & 1;
    const int cg = tid & 31;

    // ---- x slice from global (coalesced row reads, one-time) ----
    float x[32][4];
    #pragma unroll
    for (int m = 0; m < 32; ++m) {
        const int j = (m << 2) | jg;
        const float4 a = *(const float4*)&Xk[j * D2 + cg * 4];
        x[m][0] = a.x; x[m][1] = a.y; x[m][2] = a.z; x[m][3] = a.w;
    }

    // ---- PsT init: P^1 = X strip transposed (coalesced: lanes = c) ----
    {
        const int c = tid & 127, rh = tid >> 7;
        float4 v; float* vp = (float*)&v;
        #pragma unroll
        for (int rr = 0; rr < 4; ++rr)
            vp[rr] = Xk[(r0s + rh * 4 + rr) * D2 + c];
        *(float4*)&PsT[c][rh * 4] = v;
    }

    // ---- acc = I + X (jg==0 tile) ----
    float acc[4][4];
    if (jg == 0) {
        #pragma unroll
        for (int rr = 0; rr < 4; ++rr) {
            const int row = r0s + rg * 4 + rr;
            const float4 a = *(const float4*)&Xk[row * D2 + cg * 4];
            acc[rr][0] = a.x + ((row == cg * 4 + 0) ? 1.0f : 0.0f);
            acc[rr][1] = a.y + ((row == cg * 4 + 1) ? 1.0f : 0.0f);
            acc[rr][2] = a.z + ((row == cg * 4 + 2) ? 1.0f : 0.0f);
            acc[rr][3] = a.w + ((row == cg * 4 + 3) ? 1.0f : 0.0f);
        }
    }
    __syncthreads();

    // ---- 9 remaining Taylor orders (x in VGPR, PsT broadcast) ----
    for (int it = 2; it <= 10; ++it) {
        float nv[4][4] = {{0.f,0.f,0.f,0.f},{0.f,0.f,0.f,0.f},
                          {0.f,0.f,0.f,0.f},{0.f,0.f,0.f,0.f}};
        #pragma unroll
        for (int m = 0; m < 32; ++m) {
            const int j = (m << 2) | jg;
            const float4 pv = *(const float4*)&PsT[j][rg * 4];
            const float p[4] = {pv.x, pv.y, pv.z, pv.w};
            #pragma unroll
            for (int rr = 0; rr < 4; ++rr)
                #pragma unroll
                for (int cc = 0; cc < 4; ++cc)
                    nv[rr][cc] = fmaf(p[rr], x[m][cc], nv[rr][cc]);
        }
        if (jg != 0) {
            float* rb = Red[jg - 1][rg * 32 + cg];
            #pragma unroll
            for (int rr = 0; rr < 4; ++rr)
                *(float4*)&rb[rr * 4] =
                    make_float4(nv[rr][0], nv[rr][1], nv[rr][2], nv[rr][3]);
        }
        __syncthreads();
        if (jg == 0) {
            #pragma unroll
            for (int g = 0; g < 3; ++g) {
                const float* rb = Red[g][rg * 32 + cg];
                #pragma unroll
                for (int rr = 0; rr < 4; ++rr) {
                    const float4 p = *(const float4*)&rb[rr * 4];
                    nv[rr][0] += p.x; nv[rr][1] += p.y;
                    nv[rr][2] += p.z; nv[rr][3] += p.w;
                }
            }
            const float inv = 1.0f / (float)it;
            #pragma unroll
            for (int rr = 0; rr < 4; ++rr)
                #pragma unroll
                for (int cc = 0; cc < 4; ++cc) {
                    nv[rr][cc] *= inv;
                    acc[rr][cc] += nv[rr][cc];
                }
            #pragma unroll
            for (int cc = 0; cc < 4; ++cc)
                *(float4*)&PsT[cg * 4 + cc][rg * 4] =
                    make_float4(nv[0][cc], nv[1][cc], nv[2][cc], nv[3][cc]);
        }
        __syncthreads();
    }

    if (jg == 0) {
        float* Ak = ACC + ((size_t)k * D2 + r0s + rg * 4) * D2;
        #pragma unroll
        for (int rr = 0; rr < 4; ++rr)
            *(float4*)&Ak[rr * D2 + cg * 4] =
                make_float4(acc[rr][0], acc[rr][1], acc[rr][2], acc[rr][3]);
    }
}

// ---------------------------------------------------------------------------
// K2: blocks 0..511 = chains, j-split across 2 waves: wave jh owns column
//     half [64jh,64jh+64); lane l holds rows l and l+64 of that half
//     (128 VGPR). Per step: 16 b128 broadcast reads -> 128 FMA (8:1),
//     cross-wave partial reduction via 512 B LDS, lgkm-only barriers,
//     NT stores free-running. blocks 512.. = label-skip zeros (b 256..511).
// ---------------------------------------------------------------------------
__global__ __launch_bounds__(128, 2) void k_prop(
    const float* __restrict__ s_in, const float* __restrict__ ACC,
    const int* __restrict__ labels, float* __restrict__ out)
{
    const int bid = blockIdx.x, tid = threadIdx.x;

    if (bid >= CHAINB) {
        const int z = bid - CHAINB;            // 0..2047
        const int b = 256 + (z >> 3);
        const int sub = z & 7;                 // 8 slabs each
        const int lab = labels[b];
        const vf4 zv = {0.f, 0.f, 0.f, 0.f};
        float* base = out + ((size_t)b * TSTEPS + sub * 8) * (K_OPS * D2);
        #pragma unroll 4
        for (int s = 0; s < 8; ++s) {
            vf4* p = (vf4*)(base + (size_t)s * K_OPS * D2);
            #pragma unroll
            for (int q = 0; q < 4; ++q) {
                const int slot = tid + q * 128;
                if ((slot >> 5) != lab) __builtin_nontemporal_store(zv, p + slot);
            }
        }
        return;
    }

    __shared__ float sbuf[D2];     // current state
    __shared__ float part[D2];     // wave-1 partial sums

    const int jh = tid >> 6;       // wave: column half
    const int l  = tid & 63;
    const int b  = bid;
    const int lab = labels[b];

    // rows l and l+64, columns [64jh, 64jh+64): 32 x float4, static unroll
    float rlo[64], rhi[64];
    {
        const float4* pl = (const float4*)(ACC + ((size_t)lab * D2 + l) * D2 + jh * 64);
        const float4* ph = (const float4*)(ACC + ((size_t)lab * D2 + l + 64) * D2 + jh * 64);
        #pragma unroll
        for (int q = 0; q < 16; ++q) {
            const float4 a = pl[q];
            rlo[4*q+0] = a.x; rlo[4*q+1] = a.y; rlo[4*q+2] = a.z; rlo[4*q+3] = a.w;
            const float4 c = ph[q];
            rhi[4*q+0] = c.x; rhi[4*q+1] = c.y; rhi[4*q+2] = c.z; rhi[4*q+3] = c.w;
        }
    }

    // init state + t=0 store (all 128 threads)
    const float s0 = s_in[((size_t)b * K_OPS + lab) * D2 + tid];
    sbuf[tid] = s0;
    float* ob = out + ((size_t)b * TSTEPS * K_OPS + lab) * D2;
    __builtin_nontemporal_store(s0, ob + tid);
    asm volatile("s_waitcnt lgkmcnt(0)\n\ts_barrier" ::: "memory");

    for (int t = 1; t < TSTEPS; ++t) {
        float p0 = 0.f, p1 = 0.f;
        const float4* s4 = (const float4*)&sbuf[jh * 64];
        #pragma unroll
        for (int q = 0; q < 16; ++q) {
            const float4 sv = s4[q];
            p0 = fmaf(rlo[4*q+0], sv.x, p0);
            p0 = fmaf(rlo[4*q+1], sv.y, p0);
            p0 = fmaf(rlo[4*q+2], sv.z, p0);
            p0 = fmaf(rlo[4*q+3], sv.w, p0);
            p1 = fmaf(rhi[4*q+0], sv.x, p1);
            p1 = fmaf(rhi[4*q+1], sv.y, p1);
            p1 = fmaf(rhi[4*q+2], sv.z, p1);
            p1 = fmaf(rhi[4*q+3], sv.w, p1);
        }
        if (jh == 1) { part[l] = p0; part[l + 64] = p1; }
        asm volatile("s_waitcnt lgkmcnt(0)\n\ts_barrier" ::: "memory");
        if (jh == 0) {
            const float y0 = p0 + part[l];
            const float y1 = p1 + part[l + 64];
            sbuf[l]      = y0;
            sbuf[l + 64] = y1;
            float* op = ob + (size_t)t * (K_OPS * D2);
            __builtin_nontemporal_store(y0, op + l);
            __builtin_nontemporal_store(y1, op + l + 64);
        }
        asm volatile("s_waitcnt lgkmcnt(0)\n\ts_barrier" ::: "memory");
    }
}

extern "C" void kernel_launch(void* const* d_in, const int* in_sizes, int n_in,
                              void* d_out, int out_size, void* d_ws, size_t ws_size,
                              hipStream_t stream) {
    const float* u_t = (const float*)d_in[0];   // [512,16]
    const float* s_t = (const float*)d_in[1];   // [512,16,128]
    const float* H   = (const float*)d_in[2];   // [16,128,128]

    float* out    = (float*)d_out;
    float* Xw     = (float*)d_ws;                       // [16,128,128] = 1 MB
    float* Aw     = Xw + K_OPS * D2 * D2;               // [16,128,128] = 1 MB
    int*   labels = (int*)(Aw + K_OPS * D2 * D2);       // [512]

    hipLaunchKernelGGL(k_xbuild, dim3(K_OPS), dim3(256), 0, stream,
                       H, u_t, Xw, labels);
    hipLaunchKernelGGL(k_taylor, dim3(TAYB + ZK1), dim3(256), 0, stream,
                       Xw, Aw, out);
    hipLaunchKernelGGL(k_prop, dim3(CHAINB + ZK2), dim3(128), 0, stream,
                       s_t, Aw, labels, out);
}

// Round 14
// 71.327 us; speedup vs baseline: 2.4005x; 1.0801x over previous
//
#include <hip/hip_runtime.h>

#define BATCH  512
#define K_OPS  16
#define D2     128
#define TSTEPS 64

#define TAYB   256                // taylor blocks in K1
#define ZK1    1024               // K1 zero blocks: 16 full slabs -> batches 0..255
#define CHAINB 512                // K2 chain blocks (1 batch, 128 thr, 2 waves)
#define ZK2    2048               // K2 zero blocks: batches 256..511, 8 slabs each

typedef float vf4 __attribute__((ext_vector_type(4)));

__device__ inline int argmax16(const float* __restrict__ ub) {
    float m = ub[0]; int lab = 0;
    #pragma unroll
    for (int j = 1; j < K_OPS; ++j) {
        const float v = ub[j];
        if (v > m) { m = v; lab = j; }
    }
    return lab;
}

// ---------------------------------------------------------------------------
// K0: X_k = S@sym(H_k) -> global, + labels. 16 blocks.
// ---------------------------------------------------------------------------
__global__ __launch_bounds__(256) void k_xbuild(
    const float* __restrict__ H, const float* __restrict__ u,
    float* __restrict__ X, int* __restrict__ labels)
{
    __shared__ float Hs[D2][132];
    const int k = blockIdx.x, tid = threadIdx.x;

    if (tid < 32) labels[k * 32 + tid] = argmax16(u + (k * 32 + tid) * K_OPS);

    const float* Hk = H + (size_t)k * D2 * D2;
    #pragma unroll
    for (int mm = 0; mm < 16; ++mm) {
        const int idx4 = tid + mm * 256;
        const float4 v = *(const float4*)&Hk[idx4 * 4];
        *(float4*)&Hs[idx4 >> 5][(idx4 & 31) * 4] = v;
    }
    __syncthreads();

    float* Xk = X + (size_t)k * D2 * D2;
    #pragma unroll 4
    for (int m = 0; m < 64; ++m) {
        const int idx = tid + m * 256;
        const int i = idx >> 7, j = idx & 127;
        const int i2 = i ^ 64;
        const float sgn = (i < 64) ? 0.5f : -0.5f;
        Xk[idx] = sgn * (Hs[i2][j] + Hs[j][i2]);
    }
}

// ---------------------------------------------------------------------------
// K1: blocks 0..255 = 10 Taylor orders (x from global X, coalesced; LDS
//     21.5 KB); blocks 256.. = full-slab zero of batches 0..255 (128 MB),
//     PLAIN stores (NT removed this round — testing NT-vs-plain write BW).
// ---------------------------------------------------------------------------
__global__ __launch_bounds__(256, 2) void k_taylor(
    const float* __restrict__ X, float* __restrict__ ACC,
    float* __restrict__ out)
{
    const int bid = blockIdx.x, tid = threadIdx.x;

    if (bid >= TAYB) {
        const int zb = bid - TAYB;
        const vf4 zv = {0.f, 0.f, 0.f, 0.f};
        vf4* base = (vf4*)(out + (size_t)zb * 16 * 2048);
        #pragma unroll 4
        for (int s = 0; s < 16; ++s) {
            vf4* p = base + (size_t)s * 512;
            p[tid]       = zv;
            p[tid + 256] = zv;
        }
        return;
    }

    __shared__ float PsT[D2][12];
    __shared__ float Red[3][64][20];

    const int k   = bid >> 4;
    const int r0s = (bid & 15) * 8;
    const float* Xk = X + (size_t)k * D2 * D2;

    const int jg = tid >> 6;
    const int rg = (tid >> 5) & 1;
    const int cg = tid & 31;

    float x[32][4];
    #pragma unroll
    for (int m = 0; m < 32; ++m) {
        const int j = (m << 2) | jg;
        const float4 a = *(const float4*)&Xk[j * D2 + cg * 4];
        x[m][0] = a.x; x[m][1] = a.y; x[m][2] = a.z; x[m][3] = a.w;
    }

    {
        const int c = tid & 127, rh = tid >> 7;
        float4 v; float* vp = (float*)&v;
        #pragma unroll
        for (int rr = 0; rr < 4; ++rr)
            vp[rr] = Xk[(r0s + rh * 4 + rr) * D2 + c];
        *(float4*)&PsT[c][rh * 4] = v;
    }

    float acc[4][4];
    if (jg == 0) {
        #pragma unroll
        for (int rr = 0; rr < 4; ++rr) {
            const int row = r0s + rg * 4 + rr;
            const float4 a = *(const float4*)&Xk[row * D2 + cg * 4];
            acc[rr][0] = a.x + ((row == cg * 4 + 0) ? 1.0f : 0.0f);
            acc[rr][1] = a.y + ((row == cg * 4 + 1) ? 1.0f : 0.0f);
            acc[rr][2] = a.z + ((row == cg * 4 + 2) ? 1.0f : 0.0f);
            acc[rr][3] = a.w + ((row == cg * 4 + 3) ? 1.0f : 0.0f);
        }
    }
    __syncthreads();

    for (int it = 2; it <= 10; ++it) {
        float nv[4][4] = {{0.f,0.f,0.f,0.f},{0.f,0.f,0.f,0.f},
                          {0.f,0.f,0.f,0.f},{0.f,0.f,0.f,0.f}};
        #pragma unroll
        for (int m = 0; m < 32; ++m) {
            const int j = (m << 2) | jg;
            const float4 pv = *(const float4*)&PsT[j][rg * 4];
            const float p[4] = {pv.x, pv.y, pv.z, pv.w};
            #pragma unroll
            for (int rr = 0; rr < 4; ++rr)
                #pragma unroll
                for (int cc = 0; cc < 4; ++cc)
                    nv[rr][cc] = fmaf(p[rr], x[m][cc], nv[rr][cc]);
        }
        if (jg != 0) {
            float* rb = Red[jg - 1][rg * 32 + cg];
            #pragma unroll
            for (int rr = 0; rr < 4; ++rr)
                *(float4*)&rb[rr * 4] =
                    make_float4(nv[rr][0], nv[rr][1], nv[rr][2], nv[rr][3]);
        }
        __syncthreads();
        if (jg == 0) {
            #pragma unroll
            for (int g = 0; g < 3; ++g) {
                const float* rb = Red[g][rg * 32 + cg];
                #pragma unroll
                for (int rr = 0; rr < 4; ++rr) {
                    const float4 p = *(const float4*)&rb[rr * 4];
                    nv[rr][0] += p.x; nv[rr][1] += p.y;
                    nv[rr][2] += p.z; nv[rr][3] += p.w;
                }
            }
            const float inv = 1.0f / (float)it;
            #pragma unroll
            for (int rr = 0; rr < 4; ++rr)
                #pragma unroll
                for (int cc = 0; cc < 4; ++cc) {
                    nv[rr][cc] *= inv;
                    acc[rr][cc] += nv[rr][cc];
                }
            #pragma unroll
            for (int cc = 0; cc < 4; ++cc)
                *(float4*)&PsT[cg * 4 + cc][rg * 4] =
                    make_float4(nv[0][cc], nv[1][cc], nv[2][cc], nv[3][cc]);
        }
        __syncthreads();
    }

    if (jg == 0) {
        float* Ak = ACC + ((size_t)k * D2 + r0s + rg * 4) * D2;
        #pragma unroll
        for (int rr = 0; rr < 4; ++rr)
            *(float4*)&Ak[rr * D2 + cg * 4] =
                make_float4(acc[rr][0], acc[rr][1], acc[rr][2], acc[rr][3]);
    }
}

// ---------------------------------------------------------------------------
// K2: blocks 0..511 = chains, wave-balanced j-split: wave jh reads column
//     half [64jh,64jh+64), produces output rows [64jh,64jh+64); partial for
//     the other half shipped via 512 B LDS. 2 lgkm-only barriers/step.
//     PLAIN stores. blocks 512.. = label-skip zeros (batches 256..511).
// ---------------------------------------------------------------------------
__global__ __launch_bounds__(128, 2) void k_prop(
    const float* __restrict__ s_in, const float* __restrict__ ACC,
    const int* __restrict__ labels, float* __restrict__ out)
{
    const int bid = blockIdx.x, tid = threadIdx.x;

    if (bid >= CHAINB) {
        const int z = bid - CHAINB;            // 0..2047
        const int b = 256 + (z >> 3);
        const int sub = z & 7;
        const int lab = labels[b];
        const vf4 zv = {0.f, 0.f, 0.f, 0.f};
        vf4* base = (vf4*)(out + ((size_t)b * TSTEPS + sub * 8) * (K_OPS * D2));
        #pragma unroll 4
        for (int s = 0; s < 8; ++s) {
            vf4* p = base + (size_t)s * 512;
            #pragma unroll
            for (int q = 0; q < 4; ++q) {
                const int slot = tid + q * 128;
                if ((slot >> 5) != lab) p[slot] = zv;
            }
        }
        return;
    }

    __shared__ float sbuf[D2];     // current state
    __shared__ float shipA[64];    // wave0 -> wave1 (rows 64..127 partial)
    __shared__ float shipB[64];    // wave1 -> wave0 (rows 0..63 partial)

    const int jh = tid >> 6;       // wave: column half AND output row half
    const int l  = tid & 63;
    const int b  = bid;
    const int lab = labels[b];

    // lane l of wave jh: rows l and l+64, columns [64jh, 64jh+64)
    float rlo[64], rhi[64];
    {
        const float4* pl = (const float4*)(ACC + ((size_t)lab * D2 + l) * D2 + jh * 64);
        const float4* ph = (const float4*)(ACC + ((size_t)lab * D2 + l + 64) * D2 + jh * 64);
        #pragma unroll
        for (int q = 0; q < 16; ++q) {
            const float4 a = pl[q];
            rlo[4*q+0] = a.x; rlo[4*q+1] = a.y; rlo[4*q+2] = a.z; rlo[4*q+3] = a.w;
            const float4 c = ph[q];
            rhi[4*q+0] = c.x; rhi[4*q+1] = c.y; rhi[4*q+2] = c.z; rhi[4*q+3] = c.w;
        }
    }

    const float s0 = s_in[((size_t)b * K_OPS + lab) * D2 + tid];
    sbuf[tid] = s0;
    float* ob = out + ((size_t)b * TSTEPS * K_OPS + lab) * D2;
    ob[tid] = s0;                          // t = 0
    asm volatile("s_waitcnt lgkmcnt(0)\n\ts_barrier" ::: "memory");

    for (int t = 1; t < TSTEPS; ++t) {
        float p0 = 0.f, p1 = 0.f;          // partials: row l / row l+64 over my cols
        const float4* s4 = (const float4*)&sbuf[jh * 64];
        #pragma unroll
        for (int q = 0; q < 16; ++q) {
            const float4 sv = s4[q];
            p0 = fmaf(rlo[4*q+0], sv.x, p0);
            p0 = fmaf(rlo[4*q+1], sv.y, p0);
            p0 = fmaf(rlo[4*q+2], sv.z, p0);
            p0 = fmaf(rlo[4*q+3], sv.w, p0);
            p1 = fmaf(rhi[4*q+0], sv.x, p1);
            p1 = fmaf(rhi[4*q+1], sv.y, p1);
            p1 = fmaf(rhi[4*q+2], sv.z, p1);
            p1 = fmaf(rhi[4*q+3], sv.w, p1);
        }
        // ship the partial belonging to the OTHER wave's output half
        if (jh == 0) shipA[l] = p1; else shipB[l] = p0;
        asm volatile("s_waitcnt lgkmcnt(0)\n\ts_barrier" ::: "memory");
        const float mine  = (jh == 0) ? p0 : p1;
        const float other = (jh == 0) ? shipB[l] : shipA[l];
        const float y = mine + other;      // my output row: jh*64 + l == tid
        sbuf[tid] = y;
        ob[(size_t)t * (K_OPS * D2) + tid] = y;
        asm volatile("s_waitcnt lgkmcnt(0)\n\ts_barrier" ::: "memory");
    }
}

extern "C" void kernel_launch(void* const* d_in, const int* in_sizes, int n_in,
                              void* d_out, int out_size, void* d_ws, size_t ws_size,
                              hipStream_t stream) {
    const float* u_t = (const float*)d_in[0];   // [512,16]
    const float* s_t = (const float*)d_in[1];   // [512,16,128]
    const float* H   = (const float*)d_in[2];   // [16,128,128]

    float* out    = (float*)d_out;
    float* Xw     = (float*)d_ws;                       // [16,128,128] = 1 MB
    float* Aw     = Xw + K_OPS * D2 * D2;               // [16,128,128] = 1 MB
    int*   labels = (int*)(Aw + K_OPS * D2 * D2);       // [512]

    hipLaunchKernelGGL(k_xbuild, dim3(K_OPS), dim3(256), 0, stream,
                       H, u_t, Xw, labels);
    hipLaunchKernelGGL(k_taylor, dim3(TAYB + ZK1), dim3(256), 0, stream,
                       Xw, Aw, out);
    hipLaunchKernelGGL(k_prop, dim3(CHAINB + ZK2), dim3(128), 0, stream,
                       s_t, Aw, labels, out);
}